// Round 6
// baseline (2589.583 us; speedup 1.0000x reference)
//
#include <hip/hip_runtime.h>

#define NL 50000
#define NS 128
#define G 160
#define GSQ (160*160)

// f -> (base index, frac weight); identical math to reference:
// f = (pos+100)*0.8 - 0.5, clipped to [0,159]; i = min(floor(f),158); w = f-i.
__device__ __forceinline__ void coordf(float pos, int& i, float& w) {
    float f = (pos + 100.0f) * 0.8f - 0.5f;
    f = fminf(fmaxf(f, 0.0f), 159.0f);
    int ii = (int)f; ii = ii > 158 ? 158 : ii;
    i = ii; w = f - (float)ii;
}

__device__ __forceinline__ void lds_add(float* p, float v) {
    __hip_atomic_fetch_add(p, v, __ATOMIC_RELAXED, __HIP_MEMORY_SCOPE_WORKGROUP);
}

__device__ __forceinline__ float frcp(float x) {
#if __has_builtin(__builtin_amdgcn_rcpf)
    return __builtin_amdgcn_rcpf(x);
#else
    return 1.0f / x;
#endif
}

// ---------------- Stage 1: projection (pure gather), all 3 passes ----------------
template<int PA, int PB, int PC>
__device__ __forceinline__ void proj_body(
    const float* __restrict__ img,
    const float* __restrict__ lors,
    float* __restrict__ contrib,
    int sa, int sb, int bx)
{
    const int wave = threadIdx.x >> 6;
    const int lane = threadIdx.x & 63;
    const int lor  = bx * 4 + wave;

    const float p1x = lors[0*NL + lor];
    const float p1y = lors[1*NL + lor];
    const float p1z = lors[2*NL + lor];
    const float dxv = lors[3*NL + lor] - p1x;
    const float dyv = lors[4*NL + lor] - p1y;
    const float dzv = lors[5*NL + lor] - p1z;
    const float len  = sqrtf(dxv*dxv + dyv*dyv + dzv*dzv);
    const float step = len * (1.0f/NS);

    float sum = 0.0f;
    #pragma unroll
    for (int q = 0; q < 2; ++q) {
        const int s = lane + q*64;
        const float t = ((float)s + 0.5f) * (1.0f/NS);
        const float pos[3] = { p1x + t*dxv, p1y + t*dyv, p1z + t*dzv };
        int ia, ib, ic; float wa, wb, wc;
        coordf(pos[PA], ia, wa);
        coordf(pos[PB], ib, wb);
        coordf(pos[PC], ic, wc);
        const float* g = img + ia*sa + ib*sb + ic;
        const float v000 = g[0],       v001 = g[1];
        const float v010 = g[sb],      v011 = g[sb + 1];
        const float v100 = g[sa],      v101 = g[sa + 1];
        const float v110 = g[sa + sb], v111 = g[sa + sb + 1];
        const float c00 = v000 + wc*(v001 - v000);
        const float c01 = v010 + wc*(v011 - v010);
        const float c10 = v100 + wc*(v101 - v100);
        const float c11 = v110 + wc*(v111 - v110);
        const float c0  = c00 + wb*(c01 - c00);
        const float c1  = c10 + wb*(c11 - c10);
        sum += c0 + wa*(c1 - c0);
    }

    #pragma unroll
    for (int off = 32; off > 0; off >>= 1)
        sum += __shfl_xor(sum, off, 64);

    if (lane == 0)
        contrib[lor] = 9.0f * step * step * sum;   // KW*(KW*step*sum)*step
}

__global__ __launch_bounds__(256) void proj_all(
    const float* __restrict__ img,
    const float* __restrict__ xl, const float* __restrict__ yl,
    const float* __restrict__ zl,
    float* __restrict__ cx, float* __restrict__ cy, float* __restrict__ cz)
{
    const int bx = blockIdx.x;
    if (blockIdx.y == 0)      proj_body<0,1,2>(img, zl, cz, GSQ, G, bx);
    else if (blockIdx.y == 1) proj_body<1,2,0>(img, xl, cx, GSQ, G, bx);
    else                      proj_body<0,1,2>(img, yl, cy, G, GSQ, bx);
}

// ---------------- Stage 2: slab backprojection, wave-balanced ----------------
// WG owns output plane p (stride-GSQ axis). Sample with slab base ia adds to
// planes ia (1-wa) and ia+1 (wa) -> plane p wants ia in {p-1, p}. f = A + B*t
// is linear in t; per 64-ray chunk each lane solves its ray's t-interval ->
// count; wave prefix-sums counts; lanes consume the flattened sample list.
// CRITICAL: every __shfl below is executed UNCONDITIONALLY by the whole wave
// (ds_bpermute from an inactive source lane is undefined); only the final
// lds_add is predicated.
template<int PS, int PR, int PC2>
__device__ __forceinline__ void slab_accum(
    float* __restrict__ plane,
    const float* __restrict__ lors,
    const float* __restrict__ contrib,
    int p, int wave, int lane, int nwaves)
{
    // Window covering ia in {p-1,p}; widened at edges for the clip margin
    // (unclipped f ranges over [-0.5, 159.5) for in-cube endpoints).
    const float glo = (p <= 1)   ? -1.0f  : (float)(p - 1);
    const float ghi = (p >= 158) ? 160.0f : (float)(p + 1);

    for (int base = wave*64; base < NL; base += nwaves*64) {
        const int r = base + lane;
        float A = 0.f, B = 0.f, AR = 0.f, BR = 0.f, AC = 0.f, BC = 0.f, cb = 0.f;
        int slo = 0, cnt = 0;
        if (r < NL) {
            const float q0 = lors[0*NL + r], q1 = lors[1*NL + r], q2 = lors[2*NL + r];
            const float d0 = lors[3*NL + r] - q0;
            const float d1 = lors[4*NL + r] - q1;
            const float d2 = lors[5*NL + r] - q2;
            const float P1[3] = { q0, q1, q2 };
            const float DV[3] = { d0, d1, d2 };
            A  = (P1[PS]  + 100.0f)*0.8f - 0.5f;  B  = DV[PS]*0.8f;
            AR = (P1[PR]  + 100.0f)*0.8f - 0.5f;  BR = DV[PR]*0.8f;
            AC = (P1[PC2] + 100.0f)*0.8f - 0.5f;  BC = DV[PC2]*0.8f;
            cb = contrib[r];
            if (B == 0.0f) {
                cnt = (A >= glo && A <= ghi) ? NS : 0;
            } else {
                const float rB = frcp(B);
                const float t1 = (glo - A) * rB, t2 = (ghi - A) * rB;
                const float tlo = fminf(t1, t2), thi = fmaxf(t1, t2);
                // s valid iff tlo <= (s+0.5)/NS <= thi; floor/ceil = <=1 pad,
                // exact per-sample recheck below filters the padding.
                float slof = floorf(tlo * (float)NS - 0.5f);
                float shif = ceilf (thi * (float)NS - 0.5f);
                slof = fmaxf(slof, 0.0f);
                shif = fminf(shif, (float)(NS - 1));
                slo = (int)slof;
                const int shi = (int)shif;
                cnt = shi - slo + 1; if (cnt < 0) cnt = 0;
            }
        }

        // exclusive prefix of counts across the wave (all lanes active)
        int pref = cnt;
        #pragma unroll
        for (int off = 1; off < 64; off <<= 1) {
            const int n = __shfl_up(pref, off, 64);
            if (lane >= off) pref += n;
        }
        const int total = __shfl(pref, 63, 64);
        const int start = pref - cnt;   // sorted non-decreasing across lanes

        for (int k0 = 0; k0 < total; k0 += 64) {
            const int k  = k0 + lane;
            const int kc = k < total ? k : total - 1;   // keep all lanes valid

            // owner j = largest lane with start_j <= kc (start_0 == 0);
            // 6-step binary search, whole wave active at every shfl.
            int j = 0;
            #pragma unroll
            for (int stp = 32; stp >= 1; stp >>= 1) {
                const int cand = j + stp;
                const int sc = __shfl(start, cand, 64);
                if (cand < 64 && sc <= kc) j = cand;
            }

            // unconditional parameter fetches (whole wave active)
            const int   sj  = __shfl(slo,   j, 64);
            const int   stj = __shfl(start, j, 64);
            const float Aj  = __shfl(A,  j, 64);
            const float Bj  = __shfl(B,  j, 64);
            const float ARj = __shfl(AR, j, 64);
            const float BRj = __shfl(BR, j, 64);
            const float ACj = __shfl(AC, j, 64);
            const float BCj = __shfl(BC, j, 64);
            const float cbj = __shfl(cb, j, 64);

            const int s = sj + (kc - stj);
            const float t = ((float)s + 0.5f) * (1.0f/NS);
            float fA = Aj + Bj * t;
            fA = fminf(fmaxf(fA, 0.0f), 159.0f);
            int ia = (int)fA; ia = ia > 158 ? 158 : ia;
            const float wa = fA - (float)ia;
            float fa;
            if (ia == p)          fa = 1.0f - wa;
            else if (ia == p - 1) fa = wa;
            else                  fa = -1.0f;

            float fR = ARj + BRj * t;
            float fC = ACj + BCj * t;
            fR = fminf(fmaxf(fR, 0.0f), 159.0f);
            fC = fminf(fmaxf(fC, 0.0f), 159.0f);
            int ib = (int)fR; ib = ib > 158 ? 158 : ib;
            int ic = (int)fC; ic = ic > 158 ? 158 : ic;
            const float wb = fR - (float)ib;
            const float wc = fC - (float)ic;

            if (k < total && fa >= 0.0f) {
                const float v  = fa * cbj;
                const float v0 = v * (1.0f - wb), v1 = v * wb;
                float* q = plane + ib*G + ic;
                lds_add(q,         v0 * (1.0f - wc));
                lds_add(q + 1,     v0 * wc);
                lds_add(q + G,     v1 * (1.0f - wc));
                lds_add(q + G + 1, v1 * wc);
            }
        }
    }
}

__global__ __launch_bounds__(1024) void bp_kernel(
    const float* __restrict__ img, const float* __restrict__ eff,
    const float* __restrict__ zl, const float* __restrict__ xl,
    const float* __restrict__ yl,
    const float* __restrict__ cz, const float* __restrict__ cx,
    const float* __restrict__ cy,
    float* __restrict__ out)
{
    __shared__ float plane[GSQ];
    const int p    = blockIdx.x;
    const int tid  = threadIdx.x;
    const int wave = tid >> 6;
    const int lane = tid & 63;

    for (int j = tid; j < GSQ; j += 1024) plane[j] = 0.0f;
    __syncthreads();

    // z-pass: base = i0*GSQ + i1*G + i2   -> slab=pos0, row=pos1, col=pos2
    slab_accum<0,1,2>(plane, zl, cz, p, wave, lane, 16);
    // x-pass: base = i1*GSQ + i2*G + i0   -> slab=pos1, row=pos2, col=pos0
    slab_accum<1,2,0>(plane, xl, cx, p, wave, lane, 16);
    // y-pass: base = i1*GSQ + i0*G + i2   -> slab=pos1, row=pos0, col=pos2
    slab_accum<1,0,2>(plane, yl, cy, p, wave, lane, 16);

    __syncthreads();

    // Fused finalize on this WG's disjoint plane.
    const int pbase = p * GSQ;
    for (int j = tid; j < GSQ; j += 1024) {
        const int idx = pbase + j;
        out[idx] = plane[j] * img[idx] * eff[idx];
    }
}

extern "C" void kernel_launch(void* const* d_in, const int* in_sizes, int n_in,
                              void* d_out, int out_size, void* d_ws, size_t ws_size,
                              hipStream_t stream) {
    const float* img = (const float*)d_in[0];
    const float* eff = (const float*)d_in[1];
    const float* xl  = (const float*)d_in[2];
    const float* yl  = (const float*)d_in[3];
    const float* zl  = (const float*)d_in[4];
    float* out = (float*)d_out;

    float* cz = (float*)d_ws;
    float* cx = cz + NL;
    float* cy = cx + NL;

    proj_all<<<dim3(NL/4, 3), dim3(256), 0, stream>>>(img, xl, yl, zl, cx, cy, cz);
    bp_kernel<<<dim3(G), dim3(1024), 0, stream>>>(img, eff, zl, xl, yl, cz, cx, cy, out);
}

// Round 7
// 1801.208 us; speedup vs baseline: 1.4377x; 1.4377x over previous
//
#include <hip/hip_runtime.h>

#define NL 50000
#define NS 128
#define G 160
#define GSQ (160*160)
#define GCUBE (160*160*160)

struct RayParam { float4 a, b; };  // a={A,B,AR,BR}  b={AC,BC,cb,pad}

// f -> (base index, frac weight); identical math to reference.
__device__ __forceinline__ void coordf(float pos, int& i, float& w) {
    float f = (pos + 100.0f) * 0.8f - 0.5f;
    f = fminf(fmaxf(f, 0.0f), 159.0f);
    int ii = (int)f; ii = ii > 158 ? 158 : ii;
    i = ii; w = f - (float)ii;
}

__device__ __forceinline__ void lds_add(float* p, float v) {
    __hip_atomic_fetch_add(p, v, __ATOMIC_RELAXED, __HIP_MEMORY_SCOPE_WORKGROUP);
}

__device__ __forceinline__ float frcp(float x) {
#if __has_builtin(__builtin_amdgcn_rcpf)
    return __builtin_amdgcn_rcpf(x);
#else
    return 1.0f / x;
#endif
}

// ---------------- Stage 1: projection (gather) + param packing ----------------
// PA,PB,PC: gather mapping (strides sa,sb,1). QS,QR,QC: bp slab/row/col
// position components for this pass (written into params for bp_split).
template<int PA, int PB, int PC, int QS, int QR, int QC>
__device__ __forceinline__ void proj_body(
    const float* __restrict__ img,
    const float* __restrict__ lors,
    float* __restrict__ contrib,
    RayParam* __restrict__ params,
    int sa, int sb, int bx)
{
    const int wave = threadIdx.x >> 6;
    const int lane = threadIdx.x & 63;
    const int lor  = bx * 4 + wave;

    const float p1x = lors[0*NL + lor];
    const float p1y = lors[1*NL + lor];
    const float p1z = lors[2*NL + lor];
    const float dxv = lors[3*NL + lor] - p1x;
    const float dyv = lors[4*NL + lor] - p1y;
    const float dzv = lors[5*NL + lor] - p1z;
    const float len  = sqrtf(dxv*dxv + dyv*dyv + dzv*dzv);
    const float step = len * (1.0f/NS);

    float sum = 0.0f;
    #pragma unroll
    for (int q = 0; q < 2; ++q) {
        const int s = lane + q*64;
        const float t = ((float)s + 0.5f) * (1.0f/NS);
        const float pos[3] = { p1x + t*dxv, p1y + t*dyv, p1z + t*dzv };
        int ia, ib, ic; float wa, wb, wc;
        coordf(pos[PA], ia, wa);
        coordf(pos[PB], ib, wb);
        coordf(pos[PC], ic, wc);
        const float* g = img + ia*sa + ib*sb + ic;
        const float v000 = g[0],       v001 = g[1];
        const float v010 = g[sb],      v011 = g[sb + 1];
        const float v100 = g[sa],      v101 = g[sa + 1];
        const float v110 = g[sa + sb], v111 = g[sa + sb + 1];
        const float c00 = v000 + wc*(v001 - v000);
        const float c01 = v010 + wc*(v011 - v010);
        const float c10 = v100 + wc*(v101 - v100);
        const float c11 = v110 + wc*(v111 - v110);
        const float c0  = c00 + wb*(c01 - c00);
        const float c1  = c10 + wb*(c11 - c10);
        sum += c0 + wa*(c1 - c0);
    }

    #pragma unroll
    for (int off = 32; off > 0; off >>= 1)
        sum += __shfl_xor(sum, off, 64);

    if (lane == 0) {
        const float cb = 9.0f * step * step * sum;   // KW*(KW*step*sum)*step
        contrib[lor] = cb;
        if (params) {
            const float P1v[3] = { p1x, p1y, p1z };
            const float DVv[3] = { dxv, dyv, dzv };
            float4 a, b;
            a.x = (P1v[QS] + 100.0f)*0.8f - 0.5f;  a.y = DVv[QS]*0.8f;
            a.z = (P1v[QR] + 100.0f)*0.8f - 0.5f;  a.w = DVv[QR]*0.8f;
            b.x = (P1v[QC] + 100.0f)*0.8f - 0.5f;  b.y = DVv[QC]*0.8f;
            b.z = cb;                               b.w = 0.0f;
            params[lor].a = a;
            params[lor].b = b;
        }
    }
}

__global__ __launch_bounds__(256) void proj_all(
    const float* __restrict__ img,
    const float* __restrict__ xl, const float* __restrict__ yl,
    const float* __restrict__ zl,
    float* __restrict__ cz, float* __restrict__ cx, float* __restrict__ cy,
    RayParam* __restrict__ params)   // may be null (fallback path)
{
    const int bx = blockIdx.x;
    // pass 0 = z: base = i0*GSQ + i1*G + i2 -> slab=pos0,row=pos1,col=pos2
    if (blockIdx.y == 0)
        proj_body<0,1,2, 0,1,2>(img, zl, cz, params ? params        : nullptr, GSQ, G, bx);
    // pass 1 = x: base = i1*GSQ + i2*G + i0 -> slab=pos1,row=pos2,col=pos0
    else if (blockIdx.y == 1)
        proj_body<1,2,0, 1,2,0>(img, xl, cx, params ? params +   NL : nullptr, GSQ, G, bx);
    // pass 2 = y: base = i1*GSQ + i0*G + i2 -> slab=pos1,row=pos0,col=pos2
    else
        proj_body<0,1,2, 1,0,2>(img, yl, cy, params ? params + 2*NL : nullptr, G, GSQ, bx);
}

// ---------------- Stage 2a: split backprojection (plane, pass) ----------------
// WG (p, pass) accumulates its pass's contribution to plane p in LDS, writes
// the partial plane to slabs[pass*GCUBE + p*GSQ ...]. Compaction as round 6;
// all __shfl executed wave-uniformly (inactive-source-lane hazard).
__global__ __launch_bounds__(1024) void bp_split(
    const RayParam* __restrict__ params,
    float* __restrict__ slabs)
{
    __shared__ float plane[GSQ];
    const int p    = blockIdx.x;
    const int pass = blockIdx.y;
    const int tid  = threadIdx.x;
    const int wave = tid >> 6;
    const int lane = tid & 63;
    const RayParam* __restrict__ pp = params + pass*NL;

    for (int j = tid; j < GSQ; j += 1024) plane[j] = 0.0f;
    __syncthreads();

    const float glo = (p <= 1)   ? -1.0f  : (float)(p - 1);
    const float ghi = (p >= 158) ? 160.0f : (float)(p + 1);

    for (int base = wave*64; base < NL; base += 16*64) {
        const int r = base + lane;
        float A = 0.f, B = 0.f, AR = 0.f, BR = 0.f, AC = 0.f, BC = 0.f, cb = 0.f;
        int slo = 0, cnt = 0;
        if (r < NL) {
            const float4 a = pp[r].a;
            const float4 b = pp[r].b;
            A = a.x; B = a.y; AR = a.z; BR = a.w;
            AC = b.x; BC = b.y; cb = b.z;
            if (B == 0.0f) {
                cnt = (A >= glo && A <= ghi) ? NS : 0;
            } else {
                const float rB = frcp(B);
                const float t1 = (glo - A) * rB, t2 = (ghi - A) * rB;
                const float tlo = fminf(t1, t2), thi = fmaxf(t1, t2);
                float slof = floorf(tlo * (float)NS - 0.5f);
                float shif = ceilf (thi * (float)NS - 0.5f);
                slof = fmaxf(slof, 0.0f);
                shif = fminf(shif, (float)(NS - 1));
                slo = (int)slof;
                const int shi = (int)shif;
                cnt = shi - slo + 1; if (cnt < 0) cnt = 0;
            }
        }

        int pref = cnt;
        #pragma unroll
        for (int off = 1; off < 64; off <<= 1) {
            const int n = __shfl_up(pref, off, 64);
            if (lane >= off) pref += n;
        }
        const int total = __shfl(pref, 63, 64);
        const int start = pref - cnt;

        for (int k0 = 0; k0 < total; k0 += 64) {
            const int k  = k0 + lane;
            const int kc = k < total ? k : total - 1;

            int j = 0;
            #pragma unroll
            for (int stp = 32; stp >= 1; stp >>= 1) {
                const int cand = j + stp;
                const int sc = __shfl(start, cand, 64);
                if (cand < 64 && sc <= kc) j = cand;
            }

            const int   sj  = __shfl(slo,   j, 64);
            const int   stj = __shfl(start, j, 64);
            const float Aj  = __shfl(A,  j, 64);
            const float Bj  = __shfl(B,  j, 64);
            const float ARj = __shfl(AR, j, 64);
            const float BRj = __shfl(BR, j, 64);
            const float ACj = __shfl(AC, j, 64);
            const float BCj = __shfl(BC, j, 64);
            const float cbj = __shfl(cb, j, 64);

            const int s = sj + (kc - stj);
            const float t = ((float)s + 0.5f) * (1.0f/NS);
            float fA = Aj + Bj * t;
            fA = fminf(fmaxf(fA, 0.0f), 159.0f);
            int ia = (int)fA; ia = ia > 158 ? 158 : ia;
            const float wa = fA - (float)ia;
            float fa;
            if (ia == p)          fa = 1.0f - wa;
            else if (ia == p - 1) fa = wa;
            else                  fa = -1.0f;

            float fR = ARj + BRj * t;
            float fC = ACj + BCj * t;
            fR = fminf(fmaxf(fR, 0.0f), 159.0f);
            fC = fminf(fmaxf(fC, 0.0f), 159.0f);
            int ib = (int)fR; ib = ib > 158 ? 158 : ib;
            int ic = (int)fC; ic = ic > 158 ? 158 : ic;
            const float wb = fR - (float)ib;
            const float wc = fC - (float)ic;

            if (k < total && fa >= 0.0f) {
                const float v  = fa * cbj;
                const float v0 = v * (1.0f - wb), v1 = v * wb;
                float* q = plane + ib*G + ic;
                lds_add(q,         v0 * (1.0f - wc));
                lds_add(q + 1,     v0 * wc);
                lds_add(q + G,     v1 * (1.0f - wc));
                lds_add(q + G + 1, v1 * wc);
            }
        }
    }
    __syncthreads();

    float* dst = slabs + (size_t)pass*GCUBE + (size_t)p*GSQ;
    for (int j4 = tid; j4 < GSQ/4; j4 += 1024) {
        float4 v;
        v.x = plane[4*j4];   v.y = plane[4*j4+1];
        v.z = plane[4*j4+2]; v.w = plane[4*j4+3];
        ((float4*)dst)[j4] = v;
    }
}

__global__ __launch_bounds__(256) void finalize_split(
    const float4* __restrict__ slabs, const float4* __restrict__ img,
    const float4* __restrict__ eff, float4* __restrict__ out)
{
    const int i = blockIdx.x * 256 + threadIdx.x;   // over GCUBE/4
    const float4 s0 = slabs[i];
    const float4 s1 = slabs[i +   GCUBE/4];
    const float4 s2 = slabs[i + 2*(GCUBE/4)];
    const float4 a = img[i];
    const float4 e = eff[i];
    float4 o;
    o.x = (s0.x + s1.x + s2.x) * a.x * e.x;
    o.y = (s0.y + s1.y + s2.y) * a.y * e.y;
    o.z = (s0.z + s1.z + s2.z) * a.z * e.z;
    o.w = (s0.w + s1.w + s2.w) * a.w * e.w;
    out[i] = o;
}

// ---------------- Stage 2b: fused fallback (round-6, proven) ----------------
template<int PS, int PR, int PC2>
__device__ __forceinline__ void slab_accum(
    float* __restrict__ plane,
    const float* __restrict__ lors,
    const float* __restrict__ contrib,
    int p, int wave, int lane, int nwaves)
{
    const float glo = (p <= 1)   ? -1.0f  : (float)(p - 1);
    const float ghi = (p >= 158) ? 160.0f : (float)(p + 1);

    for (int base = wave*64; base < NL; base += nwaves*64) {
        const int r = base + lane;
        float A = 0.f, B = 0.f, AR = 0.f, BR = 0.f, AC = 0.f, BC = 0.f, cb = 0.f;
        int slo = 0, cnt = 0;
        if (r < NL) {
            const float q0 = lors[0*NL + r], q1 = lors[1*NL + r], q2 = lors[2*NL + r];
            const float d0 = lors[3*NL + r] - q0;
            const float d1 = lors[4*NL + r] - q1;
            const float d2 = lors[5*NL + r] - q2;
            const float P1[3] = { q0, q1, q2 };
            const float DV[3] = { d0, d1, d2 };
            A  = (P1[PS]  + 100.0f)*0.8f - 0.5f;  B  = DV[PS]*0.8f;
            AR = (P1[PR]  + 100.0f)*0.8f - 0.5f;  BR = DV[PR]*0.8f;
            AC = (P1[PC2] + 100.0f)*0.8f - 0.5f;  BC = DV[PC2]*0.8f;
            cb = contrib[r];
            if (B == 0.0f) {
                cnt = (A >= glo && A <= ghi) ? NS : 0;
            } else {
                const float rB = frcp(B);
                const float t1 = (glo - A) * rB, t2 = (ghi - A) * rB;
                const float tlo = fminf(t1, t2), thi = fmaxf(t1, t2);
                float slof = floorf(tlo * (float)NS - 0.5f);
                float shif = ceilf (thi * (float)NS - 0.5f);
                slof = fmaxf(slof, 0.0f);
                shif = fminf(shif, (float)(NS - 1));
                slo = (int)slof;
                const int shi = (int)shif;
                cnt = shi - slo + 1; if (cnt < 0) cnt = 0;
            }
        }

        int pref = cnt;
        #pragma unroll
        for (int off = 1; off < 64; off <<= 1) {
            const int n = __shfl_up(pref, off, 64);
            if (lane >= off) pref += n;
        }
        const int total = __shfl(pref, 63, 64);
        const int start = pref - cnt;

        for (int k0 = 0; k0 < total; k0 += 64) {
            const int k  = k0 + lane;
            const int kc = k < total ? k : total - 1;

            int j = 0;
            #pragma unroll
            for (int stp = 32; stp >= 1; stp >>= 1) {
                const int cand = j + stp;
                const int sc = __shfl(start, cand, 64);
                if (cand < 64 && sc <= kc) j = cand;
            }

            const int   sj  = __shfl(slo,   j, 64);
            const int   stj = __shfl(start, j, 64);
            const float Aj  = __shfl(A,  j, 64);
            const float Bj  = __shfl(B,  j, 64);
            const float ARj = __shfl(AR, j, 64);
            const float BRj = __shfl(BR, j, 64);
            const float ACj = __shfl(AC, j, 64);
            const float BCj = __shfl(BC, j, 64);
            const float cbj = __shfl(cb, j, 64);

            const int s = sj + (kc - stj);
            const float t = ((float)s + 0.5f) * (1.0f/NS);
            float fA = Aj + Bj * t;
            fA = fminf(fmaxf(fA, 0.0f), 159.0f);
            int ia = (int)fA; ia = ia > 158 ? 158 : ia;
            const float wa = fA - (float)ia;
            float fa;
            if (ia == p)          fa = 1.0f - wa;
            else if (ia == p - 1) fa = wa;
            else                  fa = -1.0f;

            float fR = ARj + BRj * t;
            float fC = ACj + BCj * t;
            fR = fminf(fmaxf(fR, 0.0f), 159.0f);
            fC = fminf(fmaxf(fC, 0.0f), 159.0f);
            int ib = (int)fR; ib = ib > 158 ? 158 : ib;
            int ic = (int)fC; ic = ic > 158 ? 158 : ic;
            const float wb = fR - (float)ib;
            const float wc = fC - (float)ic;

            if (k < total && fa >= 0.0f) {
                const float v  = fa * cbj;
                const float v0 = v * (1.0f - wb), v1 = v * wb;
                float* q = plane + ib*G + ic;
                lds_add(q,         v0 * (1.0f - wc));
                lds_add(q + 1,     v0 * wc);
                lds_add(q + G,     v1 * (1.0f - wc));
                lds_add(q + G + 1, v1 * wc);
            }
        }
    }
}

__global__ __launch_bounds__(1024) void bp_fused(
    const float* __restrict__ img, const float* __restrict__ eff,
    const float* __restrict__ zl, const float* __restrict__ xl,
    const float* __restrict__ yl,
    const float* __restrict__ cz, const float* __restrict__ cx,
    const float* __restrict__ cy,
    float* __restrict__ out)
{
    __shared__ float plane[GSQ];
    const int p    = blockIdx.x;
    const int tid  = threadIdx.x;
    const int wave = tid >> 6;
    const int lane = tid & 63;

    for (int j = tid; j < GSQ; j += 1024) plane[j] = 0.0f;
    __syncthreads();

    slab_accum<0,1,2>(plane, zl, cz, p, wave, lane, 16);
    slab_accum<1,2,0>(plane, xl, cx, p, wave, lane, 16);
    slab_accum<1,0,2>(plane, yl, cy, p, wave, lane, 16);

    __syncthreads();

    const int pbase = p * GSQ;
    for (int j = tid; j < GSQ; j += 1024) {
        const int idx = pbase + j;
        out[idx] = plane[j] * img[idx] * eff[idx];
    }
}

extern "C" void kernel_launch(void* const* d_in, const int* in_sizes, int n_in,
                              void* d_out, int out_size, void* d_ws, size_t ws_size,
                              hipStream_t stream) {
    const float* img = (const float*)d_in[0];
    const float* eff = (const float*)d_in[1];
    const float* xl  = (const float*)d_in[2];
    const float* yl  = (const float*)d_in[3];
    const float* zl  = (const float*)d_in[4];
    float* out = (float*)d_out;

    const size_t CONTRIB_B = (size_t)3*NL*sizeof(float);     // 600 KB
    const size_t PARAMS_B  = (size_t)3*NL*sizeof(RayParam);  // 4.8 MB
    const size_t SLABS_B   = (size_t)3*GCUBE*sizeof(float);  // 49.2 MB

    char* w = (char*)d_ws;
    float*    cz     = (float*)w;
    float*    cx     = cz + NL;
    float*    cy     = cx + NL;
    RayParam* params = (RayParam*)(w + CONTRIB_B);
    float*    slabs  = (float*)(w + CONTRIB_B + PARAMS_B);

    const bool split = ws_size >= CONTRIB_B + PARAMS_B + SLABS_B;

    proj_all<<<dim3(NL/4, 3), dim3(256), 0, stream>>>(
        img, xl, yl, zl, cz, cx, cy, split ? params : nullptr);

    if (split) {
        bp_split<<<dim3(G, 3), dim3(1024), 0, stream>>>(params, slabs);
        finalize_split<<<dim3(GCUBE/4/256), dim3(256), 0, stream>>>(
            (const float4*)slabs, (const float4*)img, (const float4*)eff,
            (float4*)out);
    } else {
        bp_fused<<<dim3(G), dim3(1024), 0, stream>>>(
            img, eff, zl, xl, yl, cz, cx, cy, out);
    }
}

// Round 8
// 1755.013 us; speedup vs baseline: 1.4755x; 1.0263x over previous
//
#include <hip/hip_runtime.h>

#define NL 50000
#define NS 128
#define G 160
#define GSQ (160*160)
#define GCUBE (160*160*160)
#define SEG 256   // owner-table window (per wave)

struct RayParam { float4 a, b; };  // a={A,B,AR,BR}  b={AC,BC,cb,pad}

// f -> (base index, frac weight); identical math to reference.
__device__ __forceinline__ void coordf(float pos, int& i, float& w) {
    float f = (pos + 100.0f) * 0.8f - 0.5f;
    f = fminf(fmaxf(f, 0.0f), 159.0f);
    int ii = (int)f; ii = ii > 158 ? 158 : ii;
    i = ii; w = f - (float)ii;
}

__device__ __forceinline__ void lds_add(float* p, float v) {
    __hip_atomic_fetch_add(p, v, __ATOMIC_RELAXED, __HIP_MEMORY_SCOPE_WORKGROUP);
}

__device__ __forceinline__ float frcp(float x) {
#if __has_builtin(__builtin_amdgcn_rcpf)
    return __builtin_amdgcn_rcpf(x);
#else
    return 1.0f / x;
#endif
}

// ---------------- Stage 1: projection (gather) + param packing ----------------
template<int PA, int PB, int PC, int QS, int QR, int QC>
__device__ __forceinline__ void proj_body(
    const float* __restrict__ img,
    const float* __restrict__ lors,
    float* __restrict__ contrib,
    RayParam* __restrict__ params,
    int sa, int sb, int bx)
{
    const int wave = threadIdx.x >> 6;
    const int lane = threadIdx.x & 63;
    const int lor  = bx * 4 + wave;

    const float p1x = lors[0*NL + lor];
    const float p1y = lors[1*NL + lor];
    const float p1z = lors[2*NL + lor];
    const float dxv = lors[3*NL + lor] - p1x;
    const float dyv = lors[4*NL + lor] - p1y;
    const float dzv = lors[5*NL + lor] - p1z;
    const float len  = sqrtf(dxv*dxv + dyv*dyv + dzv*dzv);
    const float step = len * (1.0f/NS);

    float sum = 0.0f;
    #pragma unroll
    for (int q = 0; q < 2; ++q) {
        const int s = lane + q*64;
        const float t = ((float)s + 0.5f) * (1.0f/NS);
        const float pos[3] = { p1x + t*dxv, p1y + t*dyv, p1z + t*dzv };
        int ia, ib, ic; float wa, wb, wc;
        coordf(pos[PA], ia, wa);
        coordf(pos[PB], ib, wb);
        coordf(pos[PC], ic, wc);
        const float* g = img + ia*sa + ib*sb + ic;
        const float v000 = g[0],       v001 = g[1];
        const float v010 = g[sb],      v011 = g[sb + 1];
        const float v100 = g[sa],      v101 = g[sa + 1];
        const float v110 = g[sa + sb], v111 = g[sa + sb + 1];
        const float c00 = v000 + wc*(v001 - v000);
        const float c01 = v010 + wc*(v011 - v010);
        const float c10 = v100 + wc*(v101 - v100);
        const float c11 = v110 + wc*(v111 - v110);
        const float c0  = c00 + wb*(c01 - c00);
        const float c1  = c10 + wb*(c11 - c10);
        sum += c0 + wa*(c1 - c0);
    }

    #pragma unroll
    for (int off = 32; off > 0; off >>= 1)
        sum += __shfl_xor(sum, off, 64);

    if (lane == 0) {
        const float cb = 9.0f * step * step * sum;   // KW*(KW*step*sum)*step
        contrib[lor] = cb;
        if (params) {
            const float P1v[3] = { p1x, p1y, p1z };
            const float DVv[3] = { dxv, dyv, dzv };
            float4 a, b;
            a.x = (P1v[QS] + 100.0f)*0.8f - 0.5f;  a.y = DVv[QS]*0.8f;
            a.z = (P1v[QR] + 100.0f)*0.8f - 0.5f;  a.w = DVv[QR]*0.8f;
            b.x = (P1v[QC] + 100.0f)*0.8f - 0.5f;  b.y = DVv[QC]*0.8f;
            b.z = cb;                               b.w = 0.0f;
            params[lor].a = a;
            params[lor].b = b;
        }
    }
}

__global__ __launch_bounds__(256) void proj_all(
    const float* __restrict__ img,
    const float* __restrict__ xl, const float* __restrict__ yl,
    const float* __restrict__ zl,
    float* __restrict__ cz, float* __restrict__ cx, float* __restrict__ cy,
    RayParam* __restrict__ params)
{
    const int bx = blockIdx.x;
    if (blockIdx.y == 0)
        proj_body<0,1,2, 0,1,2>(img, zl, cz, params ? params        : nullptr, GSQ, G, bx);
    else if (blockIdx.y == 1)
        proj_body<1,2,0, 1,2,0>(img, xl, cx, params ? params +   NL : nullptr, GSQ, G, bx);
    else
        proj_body<0,1,2, 1,0,2>(img, yl, cy, params ? params + 2*NL : nullptr, G, GSQ, bx);
}

// ---------------- Stage 2a: split backprojection (plane, pass) ----------------
// Compaction via prefix scan + LDS owner table (replaces per-sample binary
// search). All __shfl executed wave-uniformly; only lds_add is predicated.
__global__ __launch_bounds__(1024) void bp_split(
    const RayParam* __restrict__ params,
    float* __restrict__ slabs)
{
    __shared__ float plane[GSQ];
    __shared__ int   owners[16*SEG];
    const int p    = blockIdx.x;
    const int pass = blockIdx.y;
    const int tid  = threadIdx.x;
    const int wave = tid >> 6;
    const int lane = tid & 63;
    const RayParam* __restrict__ pp = params + pass*NL;
    int* __restrict__ own = owners + wave*SEG;

    for (int j = tid; j < GSQ; j += 1024) plane[j] = 0.0f;
    __syncthreads();

    const float glo = (p <= 1)   ? -1.0f  : (float)(p - 1);
    const float ghi = (p >= 158) ? 160.0f : (float)(p + 1);

    for (int base = wave*64; base < NL; base += 16*64) {
        const int r = base + lane;
        float A = 0.f, B = 0.f, AR = 0.f, BR = 0.f, AC = 0.f, BC = 0.f, cb = 0.f;
        int slo = 0, cnt = 0;
        if (r < NL) {
            const float4 a = pp[r].a;
            const float4 b = pp[r].b;
            A = a.x; B = a.y; AR = a.z; BR = a.w;
            AC = b.x; BC = b.y; cb = b.z;
            if (B == 0.0f) {
                cnt = (A >= glo && A <= ghi) ? NS : 0;
            } else {
                const float rB = frcp(B);
                const float t1 = (glo - A) * rB, t2 = (ghi - A) * rB;
                const float tlo = fminf(t1, t2), thi = fmaxf(t1, t2);
                // exact: slo = ceil(tlo*NS - 0.5), shi = floor(thi*NS - 0.5);
                // 0.25-sample safety in the INCLUSIVE direction only; the
                // per-sample recheck (fa >= 0) filters the padding.
                float slof = ceilf (tlo * (float)NS - 0.75f);
                float shif = floorf(thi * (float)NS - 0.25f);
                slof = fmaxf(slof, 0.0f);
                shif = fminf(shif, (float)(NS - 1));
                slo = (int)slof;
                const int shi = (int)shif;
                cnt = shi - slo + 1; if (cnt < 0) cnt = 0;
            }
        }

        // exclusive prefix of counts across the wave (all lanes active)
        int pref = cnt;
        #pragma unroll
        for (int off = 1; off < 64; off <<= 1) {
            const int n = __shfl_up(pref, off, 64);
            if (lane >= off) pref += n;
        }
        const int total = __shfl(pref, 63, 64);
        const int start = pref - cnt;

        for (int seg = 0; seg < total; seg += SEG) {
            const int segend = seg + SEG < total ? seg + SEG : total;

            // write owner table for this window (wave-private, wave-ordered LDS)
            const int lo = start     > seg    ? start     : seg;
            const int hi = start+cnt < segend ? start+cnt : segend;
            for (int i = lo; i < hi; ++i) own[i - seg] = lane;

            for (int k0 = seg; k0 < segend; k0 += 64) {
                const int k  = k0 + lane;
                const int kc = k < segend ? k : segend - 1;

                const int j = own[kc - seg];

                // unconditional parameter fetches (whole wave active)
                const int   sj  = __shfl(slo,   j, 64);
                const int   stj = __shfl(start, j, 64);
                const float Aj  = __shfl(A,  j, 64);
                const float Bj  = __shfl(B,  j, 64);
                const float ARj = __shfl(AR, j, 64);
                const float BRj = __shfl(BR, j, 64);
                const float ACj = __shfl(AC, j, 64);
                const float BCj = __shfl(BC, j, 64);
                const float cbj = __shfl(cb, j, 64);

                const int s = sj + (kc - stj);
                const float t = ((float)s + 0.5f) * (1.0f/NS);
                float fA = Aj + Bj * t;
                fA = fminf(fmaxf(fA, 0.0f), 159.0f);
                int ia = (int)fA; ia = ia > 158 ? 158 : ia;
                const float wa = fA - (float)ia;
                float fa;
                if (ia == p)          fa = 1.0f - wa;
                else if (ia == p - 1) fa = wa;
                else                  fa = -1.0f;

                float fR = ARj + BRj * t;
                float fC = ACj + BCj * t;
                fR = fminf(fmaxf(fR, 0.0f), 159.0f);
                fC = fminf(fmaxf(fC, 0.0f), 159.0f);
                int ib = (int)fR; ib = ib > 158 ? 158 : ib;
                int ic = (int)fC; ic = ic > 158 ? 158 : ic;
                const float wb = fR - (float)ib;
                const float wc = fC - (float)ic;

                if (k < segend && fa >= 0.0f) {
                    const float v  = fa * cbj;
                    const float v0 = v * (1.0f - wb), v1 = v * wb;
                    float* q = plane + ib*G + ic;
                    lds_add(q,         v0 * (1.0f - wc));
                    lds_add(q + 1,     v0 * wc);
                    lds_add(q + G,     v1 * (1.0f - wc));
                    lds_add(q + G + 1, v1 * wc);
                }
            }
        }
    }
    __syncthreads();

    float* dst = slabs + (size_t)pass*GCUBE + (size_t)p*GSQ;
    for (int j4 = tid; j4 < GSQ/4; j4 += 1024) {
        float4 v;
        v.x = plane[4*j4];   v.y = plane[4*j4+1];
        v.z = plane[4*j4+2]; v.w = plane[4*j4+3];
        ((float4*)dst)[j4] = v;
    }
}

__global__ __launch_bounds__(256) void finalize_split(
    const float4* __restrict__ slabs, const float4* __restrict__ img,
    const float4* __restrict__ eff, float4* __restrict__ out)
{
    const int i = blockIdx.x * 256 + threadIdx.x;   // over GCUBE/4
    const float4 s0 = slabs[i];
    const float4 s1 = slabs[i +   GCUBE/4];
    const float4 s2 = slabs[i + 2*(GCUBE/4)];
    const float4 a = img[i];
    const float4 e = eff[i];
    float4 o;
    o.x = (s0.x + s1.x + s2.x) * a.x * e.x;
    o.y = (s0.y + s1.y + s2.y) * a.y * e.y;
    o.z = (s0.z + s1.z + s2.z) * a.z * e.z;
    o.w = (s0.w + s1.w + s2.w) * a.w * e.w;
    out[i] = o;
}

// ---------------- Stage 2b: fused fallback (round-6, proven) ----------------
template<int PS, int PR, int PC2>
__device__ __forceinline__ void slab_accum(
    float* __restrict__ plane,
    const float* __restrict__ lors,
    const float* __restrict__ contrib,
    int p, int wave, int lane, int nwaves)
{
    const float glo = (p <= 1)   ? -1.0f  : (float)(p - 1);
    const float ghi = (p >= 158) ? 160.0f : (float)(p + 1);

    for (int base = wave*64; base < NL; base += nwaves*64) {
        const int r = base + lane;
        float A = 0.f, B = 0.f, AR = 0.f, BR = 0.f, AC = 0.f, BC = 0.f, cb = 0.f;
        int slo = 0, cnt = 0;
        if (r < NL) {
            const float q0 = lors[0*NL + r], q1 = lors[1*NL + r], q2 = lors[2*NL + r];
            const float d0 = lors[3*NL + r] - q0;
            const float d1 = lors[4*NL + r] - q1;
            const float d2 = lors[5*NL + r] - q2;
            const float P1[3] = { q0, q1, q2 };
            const float DV[3] = { d0, d1, d2 };
            A  = (P1[PS]  + 100.0f)*0.8f - 0.5f;  B  = DV[PS]*0.8f;
            AR = (P1[PR]  + 100.0f)*0.8f - 0.5f;  BR = DV[PR]*0.8f;
            AC = (P1[PC2] + 100.0f)*0.8f - 0.5f;  BC = DV[PC2]*0.8f;
            cb = contrib[r];
            if (B == 0.0f) {
                cnt = (A >= glo && A <= ghi) ? NS : 0;
            } else {
                const float rB = frcp(B);
                const float t1 = (glo - A) * rB, t2 = (ghi - A) * rB;
                const float tlo = fminf(t1, t2), thi = fmaxf(t1, t2);
                float slof = floorf(tlo * (float)NS - 0.5f);
                float shif = ceilf (thi * (float)NS - 0.5f);
                slof = fmaxf(slof, 0.0f);
                shif = fminf(shif, (float)(NS - 1));
                slo = (int)slof;
                const int shi = (int)shif;
                cnt = shi - slo + 1; if (cnt < 0) cnt = 0;
            }
        }

        int pref = cnt;
        #pragma unroll
        for (int off = 1; off < 64; off <<= 1) {
            const int n = __shfl_up(pref, off, 64);
            if (lane >= off) pref += n;
        }
        const int total = __shfl(pref, 63, 64);
        const int start = pref - cnt;

        for (int k0 = 0; k0 < total; k0 += 64) {
            const int k  = k0 + lane;
            const int kc = k < total ? k : total - 1;

            int j = 0;
            #pragma unroll
            for (int stp = 32; stp >= 1; stp >>= 1) {
                const int cand = j + stp;
                const int sc = __shfl(start, cand, 64);
                if (cand < 64 && sc <= kc) j = cand;
            }

            const int   sj  = __shfl(slo,   j, 64);
            const int   stj = __shfl(start, j, 64);
            const float Aj  = __shfl(A,  j, 64);
            const float Bj  = __shfl(B,  j, 64);
            const float ARj = __shfl(AR, j, 64);
            const float BRj = __shfl(BR, j, 64);
            const float ACj = __shfl(AC, j, 64);
            const float BCj = __shfl(BC, j, 64);
            const float cbj = __shfl(cb, j, 64);

            const int s = sj + (kc - stj);
            const float t = ((float)s + 0.5f) * (1.0f/NS);
            float fA = Aj + Bj * t;
            fA = fminf(fmaxf(fA, 0.0f), 159.0f);
            int ia = (int)fA; ia = ia > 158 ? 158 : ia;
            const float wa = fA - (float)ia;
            float fa;
            if (ia == p)          fa = 1.0f - wa;
            else if (ia == p - 1) fa = wa;
            else                  fa = -1.0f;

            float fR = ARj + BRj * t;
            float fC = ACj + BCj * t;
            fR = fminf(fmaxf(fR, 0.0f), 159.0f);
            fC = fminf(fmaxf(fC, 0.0f), 159.0f);
            int ib = (int)fR; ib = ib > 158 ? 158 : ib;
            int ic = (int)fC; ic = ic > 158 ? 158 : ic;
            const float wb = fR - (float)ib;
            const float wc = fC - (float)ic;

            if (k < total && fa >= 0.0f) {
                const float v  = fa * cbj;
                const float v0 = v * (1.0f - wb), v1 = v * wb;
                float* q = plane + ib*G + ic;
                lds_add(q,         v0 * (1.0f - wc));
                lds_add(q + 1,     v0 * wc);
                lds_add(q + G,     v1 * (1.0f - wc));
                lds_add(q + G + 1, v1 * wc);
            }
        }
    }
}

__global__ __launch_bounds__(1024) void bp_fused(
    const float* __restrict__ img, const float* __restrict__ eff,
    const float* __restrict__ zl, const float* __restrict__ xl,
    const float* __restrict__ yl,
    const float* __restrict__ cz, const float* __restrict__ cx,
    const float* __restrict__ cy,
    float* __restrict__ out)
{
    __shared__ float plane[GSQ];
    const int p    = blockIdx.x;
    const int tid  = threadIdx.x;
    const int wave = tid >> 6;
    const int lane = tid & 63;

    for (int j = tid; j < GSQ; j += 1024) plane[j] = 0.0f;
    __syncthreads();

    slab_accum<0,1,2>(plane, zl, cz, p, wave, lane, 16);
    slab_accum<1,2,0>(plane, xl, cx, p, wave, lane, 16);
    slab_accum<1,0,2>(plane, yl, cy, p, wave, lane, 16);

    __syncthreads();

    const int pbase = p * GSQ;
    for (int j = tid; j < GSQ; j += 1024) {
        const int idx = pbase + j;
        out[idx] = plane[j] * img[idx] * eff[idx];
    }
}

extern "C" void kernel_launch(void* const* d_in, const int* in_sizes, int n_in,
                              void* d_out, int out_size, void* d_ws, size_t ws_size,
                              hipStream_t stream) {
    const float* img = (const float*)d_in[0];
    const float* eff = (const float*)d_in[1];
    const float* xl  = (const float*)d_in[2];
    const float* yl  = (const float*)d_in[3];
    const float* zl  = (const float*)d_in[4];
    float* out = (float*)d_out;

    const size_t CONTRIB_B = (size_t)3*NL*sizeof(float);     // 600 KB
    const size_t PARAMS_B  = (size_t)3*NL*sizeof(RayParam);  // 4.8 MB
    const size_t SLABS_B   = (size_t)3*GCUBE*sizeof(float);  // 49.2 MB

    char* w = (char*)d_ws;
    float*    cz     = (float*)w;
    float*    cx     = cz + NL;
    float*    cy     = cx + NL;
    RayParam* params = (RayParam*)(w + CONTRIB_B);
    float*    slabs  = (float*)(w + CONTRIB_B + PARAMS_B);

    const bool split = ws_size >= CONTRIB_B + PARAMS_B + SLABS_B;

    proj_all<<<dim3(NL/4, 3), dim3(256), 0, stream>>>(
        img, xl, yl, zl, cz, cx, cy, split ? params : nullptr);

    if (split) {
        bp_split<<<dim3(G, 3), dim3(1024), 0, stream>>>(params, slabs);
        finalize_split<<<dim3(GCUBE/4/256), dim3(256), 0, stream>>>(
            (const float4*)slabs, (const float4*)img, (const float4*)eff,
            (float4*)out);
    } else {
        bp_fused<<<dim3(G), dim3(1024), 0, stream>>>(
            img, eff, zl, xl, yl, cz, cx, cy, out);
    }
}